// Round 9
// baseline (151.448 us; speedup 1.0000x reference)
//
#include <hip/hip_runtime.h>
#include <cmath>

#define BB 128
#define TT 4096
#define NN 48

typedef short bf16x8 __attribute__((ext_vector_type(8)));
typedef short bf16x4 __attribute__((ext_vector_type(4)));
typedef float f32x4 __attribute__((ext_vector_type(4)));
typedef int   i32x4 __attribute__((ext_vector_type(4)));
typedef int   i32x2 __attribute__((ext_vector_type(2)));

__device__ __forceinline__ float wave_reduce_sum(float v) {
  #pragma unroll
  for (int m = 32; m >= 1; m >>= 1) v += __shfl_xor(v, m, 64);
  return v;
}
__device__ __forceinline__ float lane_bcast(float x, int lane) {
  return __uint_as_float((unsigned)__builtin_amdgcn_readlane(__float_as_int(x), lane));
}
__device__ __forceinline__ int cvt_pk_bf16(float lo, float hi) {
  int r;
  asm("v_cvt_pk_bf16_f32 %0, %1, %2" : "=v"(r) : "v"(lo), "v"(hi));
  return r;
}
__device__ __forceinline__ unsigned short f2bf(float f) {  // RNE f32->bf16
  unsigned u = __float_as_uint(f);
  unsigned r = (u + 0x7FFFu + ((u >> 16) & 1u)) >> 16;
  return (unsigned short)r;
}

// ---------------- Phase 1: per-(batch,chunk) transition-matrix product ----
// One wave per (b,c). Chain Y <- diag(w_t) * E^T * Y  (Y as MFMA B-operand,
// static A = E^T/48), K-space relabel so C-words == next B-words verbatim
// (verified R4-R8, absmax 0.0).
// R9: NO cross-lane w distribution at all. Each lane directly loads the em
// values for the 12 ROWS it owns (columns 16mt+4g..+3 of row t -- contiguous,
// so 3x dwordx4 loads; 16 lanes/group share the address -> L1 broadcast),
// then computes 12 exps in-lane. Removes all DS ops (R8: DS pipe ~47% busy
// with bperm latency+lgkmcnt on the step chain), the DPP/pack/unpack, and
// the w double-buffer. Emission rows double-buffered 2 steps ahead.
template<int NC, int CL>
__global__ __launch_bounds__(64) __attribute__((amdgpu_waves_per_eu(4, 4)))
void crf_chunk_kernel(const float* __restrict__ em,
                      const float* __restrict__ trans,
                      const int* __restrict__ tags,
                      unsigned short* __restrict__ G,
                      float* __restrict__ sc_part) {
  const int blk = blockIdx.x;
  const int b = blk / NC;
  const int c = blk % NC;
  const int l = threadIdx.x;
  const int g = l >> 4;
  const int rr = l & 15;
  const float FSCALE = 1.0f / 48.0f;

  // ---- static A = E^T/48. K-tile0 (16x16x32): label phi(g,e)=16*(e>>2)+4g+(e&3)
  //      K-tile1 (16x16x16): label psi(g,e)=32+4g+e
  bf16x8 Af0[3];
  bf16x4 Af1[3];
  #pragma unroll
  for (int mt = 0; mt < 3; ++mt) {
    const int i = 16 * mt + rr;
    bf16x8 a0;
    bf16x4 a1;
    #pragma unroll
    for (int e = 0; e < 8; ++e) {
      int k0 = 16 * (e >> 2) + 4 * g + (e & 3);
      a0[e] = (short)f2bf(__expf(trans[k0 * NN + i]) * FSCALE);
    }
    #pragma unroll
    for (int e = 0; e < 4; ++e) {
      int k1 = 32 + 4 * g + e;
      a1[e] = (short)f2bf(__expf(trans[k1 * NN + i]) * FSCALE);
    }
    Af0[mt] = a0; Af1[mt] = a1;
  }

  // ---- persistent state: Y = I in B-quad encoding.
  // B0s[nt] word w -> rows (16*(w>>1) + 4g + 2*(w&1), +1), col 16nt+rr
  // B1s[nt] word w -> rows (32 + 4g + 2w, +1)
  i32x4 B0s[3];
  i32x2 B1s[3];
  #pragma unroll
  for (int nt = 0; nt < 3; ++nt) {
    const int col = 16 * nt + rr;
    i32x4 b0;
    i32x2 b1;
    #pragma unroll
    for (int w = 0; w < 4; ++w) {
      int r0 = 16 * (w >> 1) + 4 * g + 2 * (w & 1);
      b0[w] = ((r0 == col) ? 0x3F80 : 0) | (((r0 + 1 == col) ? 0x3F80 : 0) << 16);
    }
    #pragma unroll
    for (int w = 0; w < 2; ++w) {
      int r0 = 32 + 4 * g + 2 * w;
      b1[w] = ((r0 == col) ? 0x3F80 : 0) | (((r0 + 1 == col) ? 0x3F80 : 0) << 16);
    }
    B0s[nt] = b0; B1s[nt] = b1;
  }

  const f32x4 zq = {0.f, 0.f, 0.f, 0.f};

  // lane's w-column base within an em row: columns 4g..4g+3 (+16 per mt)
  const float* embq = em + (size_t)b * TT * NN + 4 * g;
  const int t0 = c * CL + 1;

  // emission row double buffer: slot A (row t), slot B (row t+1); 2-step lead
  float4 qa0, qa1, qa2, qb0, qb1, qb2;
  {
    const float* p0 = embq + (size_t)t0 * NN;
    qa0 = *(const float4*)(p0 +  0); qa1 = *(const float4*)(p0 + 16); qa2 = *(const float4*)(p0 + 32);
    qb0 = *(const float4*)(p0 + 48); qb1 = *(const float4*)(p0 + 64); qb2 = *(const float4*)(p0 + 80);
  }
  const float* pb = embq + (size_t)(t0 + 2) * NN;  // prefetch base

  // 12 exps from this slot's buffered row; w<mt><r> = exp(em[t][16mt+4g+r])
  #define EXPS(Q0, Q1, Q2)                                                     \
    float w00_=__expf((Q0).x), w01_=__expf((Q0).y), w02_=__expf((Q0).z), w03_=__expf((Q0).w); \
    float w10_=__expf((Q1).x), w11_=__expf((Q1).y), w12_=__expf((Q1).z), w13_=__expf((Q1).w); \
    float w20_=__expf((Q2).x), w21_=__expf((Q2).y), w22_=__expf((Q2).z), w23_=__expf((Q2).w);

  #define BODY() do {                                                          \
    _Pragma("unroll") for (int nt = 0; nt < 3; ++nt) {                         \
      bf16x4 b1c_ = __builtin_bit_cast(bf16x4, B1s[nt]);                       \
      bf16x8 b0c_ = __builtin_bit_cast(bf16x8, B0s[nt]);                       \
      f32x4 a0_ = __builtin_amdgcn_mfma_f32_16x16x16bf16_1k(Af1[0], b1c_, zq, 0, 0, 0); \
      f32x4 a1_ = __builtin_amdgcn_mfma_f32_16x16x16bf16_1k(Af1[1], b1c_, zq, 0, 0, 0); \
      f32x4 a2_ = __builtin_amdgcn_mfma_f32_16x16x16bf16_1k(Af1[2], b1c_, zq, 0, 0, 0); \
      a0_ = __builtin_amdgcn_mfma_f32_16x16x32_bf16(Af0[0], b0c_, a0_, 0, 0, 0); \
      a1_ = __builtin_amdgcn_mfma_f32_16x16x32_bf16(Af0[1], b0c_, a1_, 0, 0, 0); \
      a2_ = __builtin_amdgcn_mfma_f32_16x16x32_bf16(Af0[2], b0c_, a2_, 0, 0, 0); \
      B0s[nt][0] = cvt_pk_bf16(a0_[0] * w00_, a0_[1] * w01_);                  \
      B0s[nt][1] = cvt_pk_bf16(a0_[2] * w02_, a0_[3] * w03_);                  \
      B0s[nt][2] = cvt_pk_bf16(a1_[0] * w10_, a1_[1] * w11_);                  \
      B0s[nt][3] = cvt_pk_bf16(a1_[2] * w12_, a1_[3] * w13_);                  \
      B1s[nt][0] = cvt_pk_bf16(a2_[0] * w20_, a2_[1] * w21_);                  \
      B1s[nt][1] = cvt_pk_bf16(a2_[2] * w22_, a2_[3] * w23_);                  \
    }                                                                          \
  } while (0)

  // fast step: consume slot, prefetch 2 rows ahead via rolling base + imm offs
  #define STEPF(Q0, Q1, Q2, POFF) do {                                         \
    EXPS(Q0, Q1, Q2)                                                           \
    Q0 = *(const float4*)(pb + (POFF) +  0);                                   \
    Q1 = *(const float4*)(pb + (POFF) + 16);                                   \
    Q2 = *(const float4*)(pb + (POFF) + 32);                                   \
    BODY();                                                                    \
  } while (0)

  // clamped step (last chunk's tail): explicit clamped row index
  #define STEPC(Q0, Q1, Q2, TROW) do {                                         \
    EXPS(Q0, Q1, Q2)                                                           \
    { const float* pc_ = embq + (size_t)(((TROW) > (TT - 1)) ? (TT - 1) : (TROW)) * NN; \
      Q0 = *(const float4*)(pc_ +  0);                                         \
      Q1 = *(const float4*)(pc_ + 16);                                         \
      Q2 = *(const float4*)(pc_ + 32); }                                       \
    BODY();                                                                    \
  } while (0)

  // no-prefetch step
  #define STEPN(Q0, Q1, Q2) do { EXPS(Q0, Q1, Q2) BODY(); } while (0)

  if (c != NC - 1) {
    // CL steps; prefetch reads <= 2 rows into the next chunk (in-bounds).
    #pragma unroll 1
    for (int it = 0; it < CL / 2; ++it) {
      STEPF(qa0, qa1, qa2, 0);
      STEPF(qb0, qb1, qb2, NN);
      pb += 2 * NN;
    }
  } else {
    // CL-1 steps: CL/2-2 fast iterations (prefetch stays <= TT-2), then 3
    // clamped/no-load steps ending exactly at t = TT-1.
    #pragma unroll 1
    for (int it = 0; it < CL / 2 - 2; ++it) {
      STEPF(qa0, qa1, qa2, 0);
      STEPF(qb0, qb1, qb2, NN);
      pb += 2 * NN;
    }
    const int tb = t0 + CL - 4;     // slots hold rows tb (A), tb+1 (B)
    STEPC(qa0, qa1, qa2, tb + 2);   // consume tb,   A <- row tb+2 (= TT-1)
    STEPC(qb0, qb1, qb2, tb + 3);   // consume tb+1, B <- clamped (unused)
    STEPN(qa0, qa1, qa2);           // consume tb+2 = TT-1
  }
  #undef STEPF
  #undef STEPC
  #undef STEPN
  #undef BODY
  #undef EXPS

  // ---- store G[i][j] = Y[j][i], row-major bf16 [48][48]; j-pairs contiguous
  unsigned short* Gc = G + (size_t)blk * (NN * NN);
  #pragma unroll
  for (int nt = 0; nt < 3; ++nt) {
    const int rowoff = (16 * nt + rr) * NN + 4 * g;
    i32x2 d0; d0[0] = B0s[nt][0]; d0[1] = B0s[nt][1];
    i32x2 d1; d1[0] = B0s[nt][2]; d1[1] = B0s[nt][3];
    i32x2 d2; d2[0] = B1s[nt][0]; d2[1] = B1s[nt][1];
    *(i32x2*)(Gc + rowoff)      = d0;
    *(i32x2*)(Gc + rowoff + 16) = d1;
    *(i32x2*)(Gc + rowoff + 32) = d2;
  }

  // ---- gold-score partial for seq slice [c*TT/NC, (c+1)*TT/NC)
  const int* tgb = tags + (size_t)b * TT;
  const float* emb = em + (size_t)b * TT * NN;
  float sc = 0.0f;
  const int base = c * (TT / NC);
  #pragma unroll
  for (int q = 0; q < TT / NC; q += 64) {
    int tt = base + q + l;
    int tg = tgb[tt];
    sc += emb[(size_t)tt * NN + tg];
    if (tt > 0) sc += trans[tgb[tt - 1] * NN + tg];
  }
  sc = wave_reduce_sum(sc);
  if (l == 0) sc_part[blk] = sc;
}

// ---------------- Phase 2: combine chunk products + finalize ------------
template<int NC>
__launch_bounds__(64, 1)
__global__ void crf_combine_kernel(const float* __restrict__ em,
                                   const float* __restrict__ startv,
                                   const float* __restrict__ endv,
                                   const int* __restrict__ tags,
                                   const unsigned short* __restrict__ G,
                                   const float* __restrict__ sc_part,
                                   float* __restrict__ out) {
  const int b = blockIdx.x;
  const int l = threadIdx.x;
  const int jc = (l < NN) ? l : (NN - 1);
  const float* emb = em + (size_t)b * TT * NN;
  const float FSCALE = 1.0f / 48.0f;

  float r = __expf(startv[jc] + emb[jc]);

  #pragma unroll 1
  for (int c = 0; c < NC; ++c) {
    const unsigned short* Gc = G + (size_t)(b * NC + c) * (NN * NN);
    float s0 = 0.f, s1 = 0.f, s2 = 0.f, s3 = 0.f;
    #pragma unroll
    for (int i = 0; i < NN; i += 4) {
      float g0 = __uint_as_float(((unsigned)Gc[(i + 0) * NN + jc]) << 16);
      float g1 = __uint_as_float(((unsigned)Gc[(i + 1) * NN + jc]) << 16);
      float g2 = __uint_as_float(((unsigned)Gc[(i + 2) * NN + jc]) << 16);
      float g3 = __uint_as_float(((unsigned)Gc[(i + 3) * NN + jc]) << 16);
      s0 = fmaf(lane_bcast(r, i + 0), g0, s0);
      s1 = fmaf(lane_bcast(r, i + 1), g1, s1);
      s2 = fmaf(lane_bcast(r, i + 2), g2, s2);
      s3 = fmaf(lane_bcast(r, i + 3), g3, s3);
    }
    r = (s0 + s1) + (s2 + s3);
  }

  float S = wave_reduce_sum((l < NN) ? r * __expf(endv[jc]) : 0.0f);
  float scp = wave_reduce_sum((l < NC) ? sc_part[b * NC + l] : 0.0f);

  if (l == 0) {
    const int* tgb = tags + (size_t)b * TT;
    double K = -log((double)FSCALE);  // exact -ln(float(1/48))
    double logZ = log((double)S) + 4095.0 * K;
    double score = (double)scp + (double)startv[tgb[0]] + (double)endv[tgb[TT - 1]];
    out[b] = (float)(logZ - score);
  }
}

extern "C" void kernel_launch(void* const* d_in, const int* in_sizes, int n_in,
                              void* d_out, int out_size, void* d_ws, size_t ws_size,
                              hipStream_t stream) {
  const float* em     = (const float*)d_in[0];
  const float* trans  = (const float*)d_in[1];
  const float* startv = (const float*)d_in[2];
  const float* endv   = (const float*)d_in[3];
  const int*   tags   = (const int*)d_in[4];
  float* out = (float*)d_out;

  // ws: [G: BB*NC*48*48 bf16][sc_part: BB*NC f32]
  const size_t need32 = (size_t)BB * 32 * NN * NN * 2 + (size_t)BB * 32 * 4;
  if (ws_size >= need32) {
    constexpr int NC = 32, CL = TT / 32;
    unsigned short* G = (unsigned short*)d_ws;
    float* sc_part = (float*)((char*)d_ws + (size_t)BB * NC * NN * NN * 2);
    hipLaunchKernelGGL((crf_chunk_kernel<NC, CL>), dim3(BB * NC), dim3(64), 0, stream,
                       em, trans, tags, G, sc_part);
    hipLaunchKernelGGL((crf_combine_kernel<NC>), dim3(BB), dim3(64), 0, stream,
                       em, startv, endv, tags, G, sc_part, out);
  } else {
    constexpr int NC = 16, CL = TT / 16;
    unsigned short* G = (unsigned short*)d_ws;
    float* sc_part = (float*)((char*)d_ws + (size_t)BB * NC * NN * NN * 2);
    hipLaunchKernelGGL((crf_chunk_kernel<NC, CL>), dim3(BB * NC), dim3(64), 0, stream,
                       em, trans, tags, G, sc_part);
    hipLaunchKernelGGL((crf_combine_kernel<NC>), dim3(BB), dim3(64), 0, stream,
                       em, startv, endv, tags, G, sc_part, out);
  }
}

// Round 11
// 141.925 us; speedup vs baseline: 1.0671x; 1.0671x over previous
//
#include <hip/hip_runtime.h>
#include <cmath>

#define BB 128
#define TT 4096
#define NN 48

typedef short bf16x8 __attribute__((ext_vector_type(8)));
typedef short bf16x4 __attribute__((ext_vector_type(4)));
typedef float f32x4 __attribute__((ext_vector_type(4)));
typedef int   i32x4 __attribute__((ext_vector_type(4)));
typedef int   i32x2 __attribute__((ext_vector_type(2)));

__device__ __forceinline__ float wave_reduce_sum(float v) {
  #pragma unroll
  for (int m = 32; m >= 1; m >>= 1) v += __shfl_xor(v, m, 64);
  return v;
}
__device__ __forceinline__ int bperm(int byteidx, int src) {
  return __builtin_amdgcn_ds_bpermute(byteidx, src);
}
__device__ __forceinline__ float lane_bcast(float x, int lane) {
  return __uint_as_float((unsigned)__builtin_amdgcn_readlane(__float_as_int(x), lane));
}
__device__ __forceinline__ int cvt_pk_bf16(float lo, float hi) {
  int r;
  asm("v_cvt_pk_bf16_f32 %0, %1, %2" : "=v"(r) : "v"(lo), "v"(hi));
  return r;
}
__device__ __forceinline__ unsigned short f2bf(float f) {  // RNE f32->bf16
  unsigned u = __float_as_uint(f);
  unsigned r = (u + 0x7FFFu + ((u >> 16) & 1u)) >> 16;
  return (unsigned short)r;
}

// ---------------- Phase 1: per-(batch,chunk) transition-matrix products ----
// R11: TWO independent chunk-chains per wave (ILP-2). Chain math is R6's
// verified step (absmax 0.0): Y <- diag(w_t) * E^T * Y with the K-space
// relabel so C-words == next B-words verbatim; w distributed per step as 12
// f32 ds_bpermute. Interleave feedA/feedB/compA/compB so each chain's
// DS+MFMA latency hides under the other chain's compute. Af shared.
template<int NC, int CL>
__global__ __launch_bounds__(64) __attribute__((amdgpu_waves_per_eu(4, 4)))
void crf_chunk_kernel(const float* __restrict__ em,
                      const float* __restrict__ trans,
                      const int* __restrict__ tags,
                      unsigned short* __restrict__ G,
                      float* __restrict__ sc_part) {
  constexpr int NP = NC / 2;
  const int blk = blockIdx.x;
  const int b = blk / NP;
  const int q = blk % NP;
  const int cA = q;
  const int cB = q + NP;
  const int l = threadIdx.x;
  const int g = l >> 4;
  const int rr = l & 15;
  const int jc = (l < NN) ? l : (NN - 1);
  const float FSCALE = 1.0f / 48.0f;

  // ---- static A = E^T/48 (shared by both chains).
  // K-tile0 (16x16x32): label phi(g,e)=16*(e>>2)+4g+(e&3)
  // K-tile1 (16x16x16): label psi(g,e)=32+4g+e
  bf16x8 Af0[3];
  bf16x4 Af1[3];
  #pragma unroll
  for (int mt = 0; mt < 3; ++mt) {
    const int i = 16 * mt + rr;
    bf16x8 a0;
    bf16x4 a1;
    #pragma unroll
    for (int e = 0; e < 8; ++e) {
      int k0 = 16 * (e >> 2) + 4 * g + (e & 3);
      a0[e] = (short)f2bf(__expf(trans[k0 * NN + i]) * FSCALE);
    }
    #pragma unroll
    for (int e = 0; e < 4; ++e) {
      int k1 = 32 + 4 * g + e;
      a1[e] = (short)f2bf(__expf(trans[k1 * NN + i]) * FSCALE);
    }
    Af0[mt] = a0; Af1[mt] = a1;
  }

  // ---- persistent state: Y = I in B-quad encoding, one copy per chain.
  i32x4 B0A[3], B0B[3];
  i32x2 B1A[3], B1B[3];
  #pragma unroll
  for (int nt = 0; nt < 3; ++nt) {
    const int col = 16 * nt + rr;
    i32x4 b0;
    i32x2 b1;
    #pragma unroll
    for (int w = 0; w < 4; ++w) {
      int r0 = 16 * (w >> 1) + 4 * g + 2 * (w & 1);
      b0[w] = ((r0 == col) ? 0x3F80 : 0) | (((r0 + 1 == col) ? 0x3F80 : 0) << 16);
    }
    #pragma unroll
    for (int w = 0; w < 2; ++w) {
      int r0 = 32 + 4 * g + 2 * w;
      b1[w] = ((r0 == col) ? 0x3F80 : 0) | (((r0 + 1 == col) ? 0x3F80 : 0) << 16);
    }
    B0A[nt] = b0; B1A[nt] = b1;
    B0B[nt] = b0; B1B[nt] = b1;
  }

  const f32x4 zq = {0.f, 0.f, 0.f, 0.f};
  const int wbyte = g << 4;  // byte idx of lane 4g (R6-verified)

  const float* embr = em + (size_t)b * TT * NN + jc;
  const int t0A = cA * CL + 1;
  const int t0B = cB * CL + 1;

  // 2-deep emission prefetch per chain
  float pfA0 = embr[(size_t)(t0A + 0) * NN];
  float pfA1 = embr[(size_t)(t0A + 1) * NN];
  float pfB0 = embr[(size_t)(t0B + 0) * NN];
  float pfB1 = embr[(size_t)(t0B + 1) * NN];
  const float* prA = embr + (size_t)(t0A + 2) * NN;
  const float* prB = embr + (size_t)(t0B + 2) * NN;

  // feeder: exp current w, reload prefetch, distribute 12 f32 w via bperm
  #define FEED(PF, LOADEXPR, WB) do {                                         \
    float w_ = __expf(PF);                                                    \
    PF = (LOADEXPR);                                                          \
    int wi_ = __float_as_int(w_);                                             \
    WB[0]  = bperm(wbyte +   0, wi_); WB[1]  = bperm(wbyte +   4, wi_);       \
    WB[2]  = bperm(wbyte +   8, wi_); WB[3]  = bperm(wbyte +  12, wi_);       \
    WB[4]  = bperm(wbyte +  64, wi_); WB[5]  = bperm(wbyte +  68, wi_);       \
    WB[6]  = bperm(wbyte +  72, wi_); WB[7]  = bperm(wbyte +  76, wi_);       \
    WB[8]  = bperm(wbyte + 128, wi_); WB[9]  = bperm(wbyte + 132, wi_);       \
    WB[10] = bperm(wbyte + 136, wi_); WB[11] = bperm(wbyte + 140, wi_);       \
  } while (0)

  #define WF(WB, k) __uint_as_float((unsigned)WB[k])

  // one chain step's matrix work (R6-verified)
  #define COMP(WB, B0, B1) do {                                               \
    _Pragma("unroll") for (int nt = 0; nt < 3; ++nt) {                        \
      bf16x4 b1c_ = __builtin_bit_cast(bf16x4, B1[nt]);                       \
      bf16x8 b0c_ = __builtin_bit_cast(bf16x8, B0[nt]);                       \
      f32x4 a0_ = __builtin_amdgcn_mfma_f32_16x16x16bf16_1k(Af1[0], b1c_, zq, 0, 0, 0); \
      f32x4 a1_ = __builtin_amdgcn_mfma_f32_16x16x16bf16_1k(Af1[1], b1c_, zq, 0, 0, 0); \
      f32x4 a2_ = __builtin_amdgcn_mfma_f32_16x16x16bf16_1k(Af1[2], b1c_, zq, 0, 0, 0); \
      a0_ = __builtin_amdgcn_mfma_f32_16x16x32_bf16(Af0[0], b0c_, a0_, 0, 0, 0); \
      a1_ = __builtin_amdgcn_mfma_f32_16x16x32_bf16(Af0[1], b0c_, a1_, 0, 0, 0); \
      a2_ = __builtin_amdgcn_mfma_f32_16x16x32_bf16(Af0[2], b0c_, a2_, 0, 0, 0); \
      B0[nt][0] = cvt_pk_bf16(a0_[0] * WF(WB,0),  a0_[1] * WF(WB,1));         \
      B0[nt][1] = cvt_pk_bf16(a0_[2] * WF(WB,2),  a0_[3] * WF(WB,3));         \
      B0[nt][2] = cvt_pk_bf16(a1_[0] * WF(WB,4),  a1_[1] * WF(WB,5));         \
      B0[nt][3] = cvt_pk_bf16(a1_[2] * WF(WB,6),  a1_[3] * WF(WB,7));         \
      B1[nt][0] = cvt_pk_bf16(a2_[0] * WF(WB,8),  a2_[1] * WF(WB,9));         \
      B1[nt][1] = cvt_pk_bf16(a2_[2] * WF(WB,10), a2_[3] * WF(WB,11));        \
    }                                                                         \
  } while (0)

  // one interleaved pair-step: feedA, feedB, compA, compB
  #define PSTEP(PFA, ALOAD, PFB, BLOAD) do {                                  \
    int wbA_[12], wbB_[12];                                                   \
    FEED(PFA, ALOAD, wbA_);                                                   \
    FEED(PFB, BLOAD, wbB_);                                                   \
    COMP(wbA_, B0A, B1A);                                                     \
    COMP(wbB_, B0B, B1B);                                                     \
  } while (0)

  if (q != NP - 1) {
    // both chains: CL full steps; prefetch reads <=2 rows into next chunk
    // (cA+1 <= NP-1 and cB+1 <= NC-1: in-bounds).
    #pragma unroll 1
    for (int it = 0; it < CL / 2; ++it) {
      PSTEP(pfA0, prA[0],  pfB0, prB[0]);
      PSTEP(pfA1, prA[NN], pfB1, prB[NN]);
      prA += 2 * NN; prB += 2 * NN;
    }
  } else {
    // chain A (cA = NP-1): CL full steps, prefetch into chunk NP (in-bounds).
    // chain B (cB = NC-1, last): CL-1 steps, last 3 with clamped prefetch.
    #pragma unroll 1
    for (int it = 0; it < CL / 2 - 2; ++it) {
      PSTEP(pfA0, prA[0],  pfB0, prB[0]);
      PSTEP(pfA1, prA[NN], pfB1, prB[NN]);
      prA += 2 * NN; prB += 2 * NN;
    }
    // state: pfA0=row t0A+CL-4, pfA1=t0A+CL-3, prA=t0A+CL-2
    //        pfB0=row TT-3,     pfB1=TT-2,     prB=TT-1
    PSTEP(pfA0, prA[0],      pfB0, prB[0]);                   // B: TT-3, load TT-1
    PSTEP(pfA1, prA[NN],     pfB1, embr[(size_t)(TT-1)*NN]);  // B: TT-2, dummy
    PSTEP(pfA0, prA[2*NN],   pfB0, embr[(size_t)(TT-1)*NN]);  // B: TT-1, dummy
    {  // final A-only step (A's 128th)
      int wbA_[12];
      FEED(pfA1, prA[3*NN], wbA_);
      COMP(wbA_, B0A, B1A);
    }
  }
  #undef PSTEP
  #undef COMP
  #undef WF
  #undef FEED

  // ---- store both G blocks: G[i][j] = Y[j][i], row-major bf16 [48][48]
  #define STOREG(CIDX, B0, B1) do {                                           \
    unsigned short* Gc_ = G + (size_t)(b * NC + (CIDX)) * (NN * NN);          \
    _Pragma("unroll") for (int nt = 0; nt < 3; ++nt) {                        \
      const int rowoff = (16 * nt + rr) * NN + 4 * g;                         \
      i32x2 d0; d0[0] = B0[nt][0]; d0[1] = B0[nt][1];                         \
      i32x2 d1; d1[0] = B0[nt][2]; d1[1] = B0[nt][3];                         \
      i32x2 d2; d2[0] = B1[nt][0]; d2[1] = B1[nt][1];                         \
      *(i32x2*)(Gc_ + rowoff)      = d0;                                      \
      *(i32x2*)(Gc_ + rowoff + 16) = d1;                                      \
      *(i32x2*)(Gc_ + rowoff + 32) = d2;                                      \
    }                                                                         \
  } while (0)
  STOREG(cA, B0A, B1A);
  STOREG(cB, B0B, B1B);
  #undef STOREG

  // ---- gold-score partials for both chunks' tag slices
  const int* tgb = tags + (size_t)b * TT;
  const float* emb = em + (size_t)b * TT * NN;
  #pragma unroll
  for (int s = 0; s < 2; ++s) {
    const int c = s ? cB : cA;
    float sc = 0.0f;
    const int base = c * (TT / NC);
    #pragma unroll
    for (int qq = 0; qq < TT / NC; qq += 64) {
      int tt = base + qq + l;
      int tg = tgb[tt];
      sc += emb[(size_t)tt * NN + tg];
      if (tt > 0) sc += trans[tgb[tt - 1] * NN + tg];
    }
    sc = wave_reduce_sum(sc);
    if (l == 0) sc_part[b * NC + c] = sc;
  }
}

// ---------------- Phase 2: combine chunk products + finalize ------------
template<int NC>
__launch_bounds__(64, 1)
__global__ void crf_combine_kernel(const float* __restrict__ em,
                                   const float* __restrict__ startv,
                                   const float* __restrict__ endv,
                                   const int* __restrict__ tags,
                                   const unsigned short* __restrict__ G,
                                   const float* __restrict__ sc_part,
                                   float* __restrict__ out) {
  const int b = blockIdx.x;
  const int l = threadIdx.x;
  const int jc = (l < NN) ? l : (NN - 1);
  const float* emb = em + (size_t)b * TT * NN;
  const float FSCALE = 1.0f / 48.0f;

  float r = __expf(startv[jc] + emb[jc]);

  #pragma unroll 1
  for (int c = 0; c < NC; ++c) {
    const unsigned short* Gc = G + (size_t)(b * NC + c) * (NN * NN);
    float s0 = 0.f, s1 = 0.f, s2 = 0.f, s3 = 0.f;
    #pragma unroll
    for (int i = 0; i < NN; i += 4) {
      float g0 = __uint_as_float(((unsigned)Gc[(i + 0) * NN + jc]) << 16);
      float g1 = __uint_as_float(((unsigned)Gc[(i + 1) * NN + jc]) << 16);
      float g2 = __uint_as_float(((unsigned)Gc[(i + 2) * NN + jc]) << 16);
      float g3 = __uint_as_float(((unsigned)Gc[(i + 3) * NN + jc]) << 16);
      s0 = fmaf(lane_bcast(r, i + 0), g0, s0);
      s1 = fmaf(lane_bcast(r, i + 1), g1, s1);
      s2 = fmaf(lane_bcast(r, i + 2), g2, s2);
      s3 = fmaf(lane_bcast(r, i + 3), g3, s3);
    }
    r = (s0 + s1) + (s2 + s3);
  }

  float S = wave_reduce_sum((l < NN) ? r * __expf(endv[jc]) : 0.0f);
  float scp = wave_reduce_sum((l < NC) ? sc_part[b * NC + l] : 0.0f);

  if (l == 0) {
    const int* tgb = tags + (size_t)b * TT;
    double K = -log((double)FSCALE);  // exact -ln(float(1/48))
    double logZ = log((double)S) + 4095.0 * K;
    double score = (double)scp + (double)startv[tgb[0]] + (double)endv[tgb[TT - 1]];
    out[b] = (float)(logZ - score);
  }
}

extern "C" void kernel_launch(void* const* d_in, const int* in_sizes, int n_in,
                              void* d_out, int out_size, void* d_ws, size_t ws_size,
                              hipStream_t stream) {
  const float* em     = (const float*)d_in[0];
  const float* trans  = (const float*)d_in[1];
  const float* startv = (const float*)d_in[2];
  const float* endv   = (const float*)d_in[3];
  const int*   tags   = (const int*)d_in[4];
  float* out = (float*)d_out;

  // ws: [G: BB*NC*48*48 bf16][sc_part: BB*NC f32]
  const size_t need32 = (size_t)BB * 32 * NN * NN * 2 + (size_t)BB * 32 * 4;
  if (ws_size >= need32) {
    constexpr int NC = 32, CL = TT / 32;
    unsigned short* G = (unsigned short*)d_ws;
    float* sc_part = (float*)((char*)d_ws + (size_t)BB * NC * NN * NN * 2);
    hipLaunchKernelGGL((crf_chunk_kernel<NC, CL>), dim3(BB * NC / 2), dim3(64), 0, stream,
                       em, trans, tags, G, sc_part);
    hipLaunchKernelGGL((crf_combine_kernel<NC>), dim3(BB), dim3(64), 0, stream,
                       em, startv, endv, tags, G, sc_part, out);
  } else {
    constexpr int NC = 16, CL = TT / 16;
    unsigned short* G = (unsigned short*)d_ws;
    float* sc_part = (float*)((char*)d_ws + (size_t)BB * NC * NN * NN * 2);
    hipLaunchKernelGGL((crf_chunk_kernel<NC, CL>), dim3(BB * NC / 2), dim3(64), 0, stream,
                       em, trans, tags, G, sc_part);
    hipLaunchKernelGGL((crf_combine_kernel<NC>), dim3(BB), dim3(64), 0, stream,
                       em, startv, endv, tags, G, sc_part, out);
  }
}

// Round 12
// 126.937 us; speedup vs baseline: 1.1931x; 1.1181x over previous
//
#include <hip/hip_runtime.h>
#include <cmath>

#define BB 128
#define TT 4096
#define NN 48

typedef short bf16x8 __attribute__((ext_vector_type(8)));
typedef short bf16x4 __attribute__((ext_vector_type(4)));
typedef float f32x4 __attribute__((ext_vector_type(4)));
typedef int   i32x4 __attribute__((ext_vector_type(4)));
typedef int   i32x2 __attribute__((ext_vector_type(2)));

__device__ __forceinline__ float wave_reduce_sum(float v) {
  #pragma unroll
  for (int m = 32; m >= 1; m >>= 1) v += __shfl_xor(v, m, 64);
  return v;
}
__device__ __forceinline__ int bperm(int byteidx, int src) {
  return __builtin_amdgcn_ds_bpermute(byteidx, src);
}
__device__ __forceinline__ float lane_bcast(float x, int lane) {
  return __uint_as_float((unsigned)__builtin_amdgcn_readlane(__float_as_int(x), lane));
}
__device__ __forceinline__ int cvt_pk_bf16(float lo, float hi) {
  int r;
  asm("v_cvt_pk_bf16_f32 %0, %1, %2" : "=v"(r) : "v"(lo), "v"(hi));
  return r;
}
__device__ __forceinline__ unsigned short f2bf(float f) {  // RNE f32->bf16
  unsigned u = __float_as_uint(f);
  unsigned r = (u + 0x7FFFu + ((u >> 16) & 1u)) >> 16;
  return (unsigned short)r;
}

// ---------------- Phase 1: per-(batch,chunk) transition-matrix product ----
// R6 host (123.5 us, absmax 0.0): Y <- diag(w_t) * E^T * Y with the K-space
// relabel so C-words == next B-words verbatim; w via 12 f32 ds_bpermute.
// R12: MFMA via inline asm with "v" constraints -> accumulators forced into
// arch VGPRs (every prior round allocated 64 VGPR + AGPRs; acc->VALU reads
// paid v_accvgpr_read ~96-144 cyc/step = the VALU excess). C operand is a
// PERSISTENT zero f32x4 with separate D -> no per-step zero-init writes.
template<int NC, int CL>
__global__ __launch_bounds__(64) __attribute__((amdgpu_waves_per_eu(4, 4)))
void crf_chunk_kernel(const float* __restrict__ em,
                      const float* __restrict__ trans,
                      const int* __restrict__ tags,
                      unsigned short* __restrict__ G,
                      float* __restrict__ sc_part) {
  const int blk = blockIdx.x;
  const int b = blk / NC;
  const int c = blk % NC;
  const int l = threadIdx.x;
  const int g = l >> 4;
  const int rr = l & 15;
  const int jc = (l < NN) ? l : (NN - 1);
  const float FSCALE = 1.0f / 48.0f;

  // ---- static A = E^T/48. K-tile0 (16x16x32): label phi(g,e)=16*(e>>2)+4g+(e&3)
  //      K-tile1 (16x16x16): label psi(g,e)=32+4g+e
  bf16x8 Af0[3];
  bf16x4 Af1[3];
  #pragma unroll
  for (int mt = 0; mt < 3; ++mt) {
    const int i = 16 * mt + rr;
    bf16x8 a0;
    bf16x4 a1;
    #pragma unroll
    for (int e = 0; e < 8; ++e) {
      int k0 = 16 * (e >> 2) + 4 * g + (e & 3);
      a0[e] = (short)f2bf(__expf(trans[k0 * NN + i]) * FSCALE);
    }
    #pragma unroll
    for (int e = 0; e < 4; ++e) {
      int k1 = 32 + 4 * g + e;
      a1[e] = (short)f2bf(__expf(trans[k1 * NN + i]) * FSCALE);
    }
    Af0[mt] = a0; Af1[mt] = a1;
  }

  // ---- persistent state: Y = I in B-quad encoding.
  i32x4 B0s[3];
  i32x2 B1s[3];
  #pragma unroll
  for (int nt = 0; nt < 3; ++nt) {
    const int col = 16 * nt + rr;
    i32x4 b0;
    i32x2 b1;
    #pragma unroll
    for (int w = 0; w < 4; ++w) {
      int r0 = 16 * (w >> 1) + 4 * g + 2 * (w & 1);
      b0[w] = ((r0 == col) ? 0x3F80 : 0) | (((r0 + 1 == col) ? 0x3F80 : 0) << 16);
    }
    #pragma unroll
    for (int w = 0; w < 2; ++w) {
      int r0 = 32 + 4 * g + 2 * w;
      b1[w] = ((r0 == col) ? 0x3F80 : 0) | (((r0 + 1 == col) ? 0x3F80 : 0) << 16);
    }
    B0s[nt] = b0; B1s[nt] = b1;
  }

  // persistent zero C operand (stays in 4 VGPRs, never rewritten)
  f32x4 zq = {0.f, 0.f, 0.f, 0.f};

  const int wbyte = g << 4;  // byte idx of lane 4g (R6-verified)

  const float* embr = em + (size_t)b * TT * NN + jc;
  const int t0 = c * CL + 1;

  // 8-deep emission prefetch (named registers)
  float pf0 = embr[(size_t)(t0 + 0) * NN];
  float pf1 = embr[(size_t)(t0 + 1) * NN];
  float pf2 = embr[(size_t)(t0 + 2) * NN];
  float pf3 = embr[(size_t)(t0 + 3) * NN];
  float pf4 = embr[(size_t)(t0 + 4) * NN];
  float pf5 = embr[(size_t)(t0 + 5) * NN];
  float pf6 = embr[(size_t)(t0 + 6) * NN];
  float pf7 = embr[(size_t)(t0 + 7) * NN];

  // core of one step, given w already in wi_
  #define BODY() do {                                                         \
    float wb_[12];                                                            \
    _Pragma("unroll") for (int mt = 0; mt < 3; ++mt)                          \
    _Pragma("unroll") for (int r = 0; r < 4; ++r)                             \
      wb_[mt * 4 + r] =                                                       \
          __uint_as_float((unsigned)bperm(wbyte + mt * 64 + r * 4, wi_));     \
    _Pragma("unroll") for (int nt = 0; nt < 3; ++nt) {                        \
      bf16x4 b1c_ = __builtin_bit_cast(bf16x4, B1s[nt]);                      \
      bf16x8 b0c_ = __builtin_bit_cast(bf16x8, B0s[nt]);                      \
      f32x4 t0_, t1_, t2_, d0_, d1_, d2_;                                     \
      asm volatile("v_mfma_f32_16x16x16_bf16 %0, %1, %2, %3"                  \
                   : "=v"(t0_) : "v"(Af1[0]), "v"(b1c_), "v"(zq));            \
      asm volatile("v_mfma_f32_16x16x16_bf16 %0, %1, %2, %3"                  \
                   : "=v"(t1_) : "v"(Af1[1]), "v"(b1c_), "v"(zq));            \
      asm volatile("v_mfma_f32_16x16x16_bf16 %0, %1, %2, %3"                  \
                   : "=v"(t2_) : "v"(Af1[2]), "v"(b1c_), "v"(zq));            \
      asm volatile("v_mfma_f32_16x16x32_bf16 %0, %1, %2, %3"                  \
                   : "=v"(d0_) : "v"(Af0[0]), "v"(b0c_), "v"(t0_));           \
      asm volatile("v_mfma_f32_16x16x32_bf16 %0, %1, %2, %3"                  \
                   : "=v"(d1_) : "v"(Af0[1]), "v"(b0c_), "v"(t1_));           \
      asm volatile("v_mfma_f32_16x16x32_bf16 %0, %1, %2, %3"                  \
                   : "=v"(d2_) : "v"(Af0[2]), "v"(b0c_), "v"(t2_));           \
      B0s[nt][0] = cvt_pk_bf16(d0_[0] * wb_[0],  d0_[1] * wb_[1]);            \
      B0s[nt][1] = cvt_pk_bf16(d0_[2] * wb_[2],  d0_[3] * wb_[3]);            \
      B0s[nt][2] = cvt_pk_bf16(d1_[0] * wb_[4],  d1_[1] * wb_[5]);            \
      B0s[nt][3] = cvt_pk_bf16(d1_[2] * wb_[6],  d1_[3] * wb_[7]);            \
      B1s[nt][0] = cvt_pk_bf16(d2_[0] * wb_[8],  d2_[1] * wb_[9]);            \
      B1s[nt][1] = cvt_pk_bf16(d2_[2] * wb_[10], d2_[3] * wb_[11]);           \
    }                                                                         \
  } while (0)

  // fast step: prefetch via pointer + folded immediate offset
  #define STEPF(PF, NPTR) do {                                                \
    float w_ = __expf(PF);                                                    \
    PF = *(NPTR);                                                             \
    int wi_ = __float_as_int(w_);                                             \
    BODY();                                                                   \
  } while (0)

  // clamped step: index form, only for the last chunk's tail
  #define STEPC(PF, NEXT_T) do {                                              \
    float w_ = __expf(PF);                                                    \
    int nxt_ = (NEXT_T) > (TT - 1) ? (TT - 1) : (NEXT_T);                     \
    PF = embr[(size_t)nxt_ * NN];                                             \
    int wi_ = __float_as_int(w_);                                             \
    BODY();                                                                   \
  } while (0)

  if (c != NC - 1) {
    // CL steps; prefetch may read up to 8 rows into the next chunk (in-bounds).
    const float* pref = embr + (size_t)(t0 + 8) * NN;
    #pragma unroll 1
    for (int it = 0; it < CL / 8; ++it) {
      STEPF(pf0, pref + 0 * NN);
      STEPF(pf1, pref + 1 * NN);
      STEPF(pf2, pref + 2 * NN);
      STEPF(pf3, pref + 3 * NN);
      STEPF(pf4, pref + 4 * NN);
      STEPF(pf5, pref + 5 * NN);
      STEPF(pf6, pref + 6 * NN);
      STEPF(pf7, pref + 7 * NN);
      pref += 8 * NN;
    }
  } else {
    // CL-1 steps. Fast for CL/8 - 2 iterations, clamped-index for the last 15.
    const float* pref = embr + (size_t)(t0 + 8) * NN;
    #pragma unroll 1
    for (int it = 0; it < CL / 8 - 2; ++it) {
      STEPF(pf0, pref + 0 * NN);
      STEPF(pf1, pref + 1 * NN);
      STEPF(pf2, pref + 2 * NN);
      STEPF(pf3, pref + 3 * NN);
      STEPF(pf4, pref + 4 * NN);
      STEPF(pf5, pref + 5 * NN);
      STEPF(pf6, pref + 6 * NN);
      STEPF(pf7, pref + 7 * NN);
      pref += 8 * NN;
    }
    const int tb = t0 + CL - 16;  // pf0..pf7 currently hold rows tb..tb+7
    STEPC(pf0, tb + 8);
    STEPC(pf1, tb + 9);
    STEPC(pf2, tb + 10);
    STEPC(pf3, tb + 11);
    STEPC(pf4, tb + 12);
    STEPC(pf5, tb + 13);
    STEPC(pf6, tb + 14);
    STEPC(pf7, tb + 15);
    STEPC(pf0, tb + 16);
    STEPC(pf1, tb + 17);
    STEPC(pf2, tb + 18);
    STEPC(pf3, tb + 19);
    STEPC(pf4, tb + 20);
    STEPC(pf5, tb + 21);
    STEPC(pf6, tb + 22);
  }
  #undef STEPF
  #undef STEPC
  #undef BODY

  // ---- store G[i][j] = Y[j][i], row-major bf16 [48][48]; j-pairs contiguous
  unsigned short* Gc = G + (size_t)blk * (NN * NN);
  #pragma unroll
  for (int nt = 0; nt < 3; ++nt) {
    const int rowoff = (16 * nt + rr) * NN + 4 * g;
    i32x2 d0; d0[0] = B0s[nt][0]; d0[1] = B0s[nt][1];
    i32x2 d1; d1[0] = B0s[nt][2]; d1[1] = B0s[nt][3];
    i32x2 d2; d2[0] = B1s[nt][0]; d2[1] = B1s[nt][1];
    *(i32x2*)(Gc + rowoff)      = d0;
    *(i32x2*)(Gc + rowoff + 16) = d1;
    *(i32x2*)(Gc + rowoff + 32) = d2;
  }

  // ---- gold-score partial for seq slice [c*TT/NC, (c+1)*TT/NC)
  const int* tgb = tags + (size_t)b * TT;
  const float* emb = em + (size_t)b * TT * NN;
  float sc = 0.0f;
  const int base = c * (TT / NC);
  #pragma unroll
  for (int q = 0; q < TT / NC; q += 64) {
    int tt = base + q + l;
    int tg = tgb[tt];
    sc += emb[(size_t)tt * NN + tg];
    if (tt > 0) sc += trans[tgb[tt - 1] * NN + tg];
  }
  sc = wave_reduce_sum(sc);
  if (l == 0) sc_part[blk] = sc;
}

// ---------------- Phase 2: combine chunk products + finalize ------------
template<int NC>
__launch_bounds__(64, 1)
__global__ void crf_combine_kernel(const float* __restrict__ em,
                                   const float* __restrict__ startv,
                                   const float* __restrict__ endv,
                                   const int* __restrict__ tags,
                                   const unsigned short* __restrict__ G,
                                   const float* __restrict__ sc_part,
                                   float* __restrict__ out) {
  const int b = blockIdx.x;
  const int l = threadIdx.x;
  const int jc = (l < NN) ? l : (NN - 1);
  const float* emb = em + (size_t)b * TT * NN;
  const float FSCALE = 1.0f / 48.0f;

  float r = __expf(startv[jc] + emb[jc]);

  #pragma unroll 1
  for (int c = 0; c < NC; ++c) {
    const unsigned short* Gc = G + (size_t)(b * NC + c) * (NN * NN);
    float s0 = 0.f, s1 = 0.f, s2 = 0.f, s3 = 0.f;
    #pragma unroll
    for (int i = 0; i < NN; i += 4) {
      float g0 = __uint_as_float(((unsigned)Gc[(i + 0) * NN + jc]) << 16);
      float g1 = __uint_as_float(((unsigned)Gc[(i + 1) * NN + jc]) << 16);
      float g2 = __uint_as_float(((unsigned)Gc[(i + 2) * NN + jc]) << 16);
      float g3 = __uint_as_float(((unsigned)Gc[(i + 3) * NN + jc]) << 16);
      s0 = fmaf(lane_bcast(r, i + 0), g0, s0);
      s1 = fmaf(lane_bcast(r, i + 1), g1, s1);
      s2 = fmaf(lane_bcast(r, i + 2), g2, s2);
      s3 = fmaf(lane_bcast(r, i + 3), g3, s3);
    }
    r = (s0 + s1) + (s2 + s3);
  }

  float S = wave_reduce_sum((l < NN) ? r * __expf(endv[jc]) : 0.0f);
  float scp = wave_reduce_sum((l < NC) ? sc_part[b * NC + l] : 0.0f);

  if (l == 0) {
    const int* tgb = tags + (size_t)b * TT;
    double K = -log((double)FSCALE);  // exact -ln(float(1/48))
    double logZ = log((double)S) + 4095.0 * K;
    double score = (double)scp + (double)startv[tgb[0]] + (double)endv[tgb[TT - 1]];
    out[b] = (float)(logZ - score);
  }
}

extern "C" void kernel_launch(void* const* d_in, const int* in_sizes, int n_in,
                              void* d_out, int out_size, void* d_ws, size_t ws_size,
                              hipStream_t stream) {
  const float* em     = (const float*)d_in[0];
  const float* trans  = (const float*)d_in[1];
  const float* startv = (const float*)d_in[2];
  const float* endv   = (const float*)d_in[3];
  const int*   tags   = (const int*)d_in[4];
  float* out = (float*)d_out;

  // ws: [G: BB*NC*48*48 bf16][sc_part: BB*NC f32]
  const size_t need32 = (size_t)BB * 32 * NN * NN * 2 + (size_t)BB * 32 * 4;
  if (ws_size >= need32) {
    constexpr int NC = 32, CL = TT / 32;
    unsigned short* G = (unsigned short*)d_ws;
    float* sc_part = (float*)((char*)d_ws + (size_t)BB * NC * NN * NN * 2);
    hipLaunchKernelGGL((crf_chunk_kernel<NC, CL>), dim3(BB * NC), dim3(64), 0, stream,
                       em, trans, tags, G, sc_part);
    hipLaunchKernelGGL((crf_combine_kernel<NC>), dim3(BB), dim3(64), 0, stream,
                       em, startv, endv, tags, G, sc_part, out);
  } else {
    constexpr int NC = 16, CL = TT / 16;
    unsigned short* G = (unsigned short*)d_ws;
    float* sc_part = (float*)((char*)d_ws + (size_t)BB * NC * NN * NN * 2);
    hipLaunchKernelGGL((crf_chunk_kernel<NC, CL>), dim3(BB * NC), dim3(64), 0, stream,
                       em, trans, tags, G, sc_part);
    hipLaunchKernelGGL((crf_combine_kernel<NC>), dim3(BB), dim3(64), 0, stream,
                       em, startv, endv, tags, G, sc_part, out);
  }
}